// Round 15
// baseline (290.943 us; speedup 1.0000x reference)
//
#include <hip/hip_runtime.h>
#include <hip/hip_bf16.h>

typedef __attribute__((ext_vector_type(8))) short short8;
typedef __attribute__((ext_vector_type(4))) float f32x4;

#define DEGPAD 16   // one counter per 64B line: kills atomic line-contention

__device__ __forceinline__ unsigned short f2bf(float x) {
    unsigned int u = __float_as_uint(x);
    u += 0x7fffu + ((u >> 16) & 1u);   // round-to-nearest-even
    return (unsigned short)(u >> 16);
}

__device__ __forceinline__ unsigned int pack2(float a, float b) {
    return (unsigned int)f2bf(a) | ((unsigned int)f2bf(b) << 16);
}

__device__ __forceinline__ float2 bf2(unsigned int u) {
    float lo = __uint_as_float(u << 16);
    float hi = __uint_as_float(u & 0xffff0000u);
    return make_float2(lo, hi);
}

// Merged: weight prep (blocks 0..575) + attention collapse (576..587) +
// degree histogram with RANK capture (588..). The atomic's return value is
// a unique within-dst rank -> deterministic CSR slot later with NO atomic.
__global__ __launch_bounds__(256) void k_misc1(
    const float* __restrict__ encW, const float* __restrict__ W,
    const float* __restrict__ We, const float* __restrict__ att_src,
    const float* __restrict__ att_dst, const float* __restrict__ att_edge,
    const int* __restrict__ dst,
    unsigned short* __restrict__ encWT16, unsigned short* __restrict__ WT16,
    float* __restrict__ we_att, float* __restrict__ wa_sd,
    int* __restrict__ deg, int* __restrict__ rank, int E_) {
    int b = blockIdx.x, t = threadIdx.x;
    if (b < 576) {
        int o = b * 256 + t;
        if (o < 16384) {
            int c = o >> 7, k = o & 127;
            encWT16[o] = f2bf(encW[k * 128 + c]);
        } else {
            int o2 = o - 16384;
            int l = o2 >> 16, r = o2 & 65535;
            int c = r >> 7, k = r & 127;
            WT16[o2] = f2bf(W[((size_t)l * 128 + k) * 512 + c]);
        }
    } else if (b < 588) {
        int o = (b - 576) * 256 + t;
        if (o < 1024) {
            int k = o >> 3, lh = o & 7, l = lh >> 2, hh = lh & 3;
            const float* wrow = We + ((size_t)(l * 128 + k)) * 512 + hh * 128;
            const float* av = att_edge + (l * 4 + hh) * 128;
            float s = 0.f;
            #pragma unroll 8
            for (int c = 0; c < 128; ++c) s = fmaf(wrow[c], av[c], s);
            we_att[o] = s;
        } else if (o < 3072) {
            int o2 = o - 1024;
            int l = o2 >> 10, r = o2 & 1023, k = r >> 3, m = r & 7, hh = m & 3;
            const float* wrow = W + ((size_t)(l * 128 + k)) * 512 + hh * 128;
            const float* av = (m < 4 ? att_src : att_dst) + (l * 4 + hh) * 128;
            float s = 0.f;
            #pragma unroll 8
            for (int c = 0; c < 128; ++c) s = fmaf(wrow[c], av[c], s);
            wa_sd[o2] = s;
        }
    } else {
        int e = (b - 588) * 256 + t;
        if (e < E_) rank[e] = atomicAdd(&deg[(size_t)dst[e] * DEGPAD], 1);
    }
}

// Block 0: exclusive scan of padded deg -> offs.  Block 1: MW/cvec collapse.
__global__ __launch_bounds__(1024) void k_scan_mw(
    const int* __restrict__ deg, int* __restrict__ offs, int n,
    const float* __restrict__ eencW, const float* __restrict__ eencb,
    const float* __restrict__ we_att,
    float* __restrict__ MW, float* __restrict__ cvec) {
    int t = threadIdx.x;
    if (blockIdx.x == 1) {
        if (t < 512) {
            int k = t >> 3, q = t & 7;
            float s = 0.f;
            #pragma unroll 8
            for (int c = 0; c < 128; ++c) s = fmaf(eencW[k * 128 + c], we_att[c * 8 + q], s);
            MW[t] = s;
        } else if (t < 520) {
            int q = t - 512;
            float s = 0.f;
            #pragma unroll 8
            for (int c = 0; c < 128; ++c) s = fmaf(eencb[c], we_att[c * 8 + q], s);
            cvec[q] = s;
        }
        return;
    }
    __shared__ int part[1024];
    int per = (n + 1023) / 1024;
    int beg = t * per, end = min(beg + per, n);
    int s = 0;
    for (int i = beg; i < end; ++i) s += deg[(size_t)i * DEGPAD];
    part[t] = s;
    __syncthreads();
    for (int off = 1; off < 1024; off <<= 1) {
        int v = (t >= off) ? part[t - off] : 0;
        __syncthreads();
        part[t] += v;
        __syncthreads();
    }
    int run = (t == 0) ? 0 : part[t - 1];
    for (int i = beg; i < end; ++i) { offs[i] = run; run += deg[(size_t)i * DEGPAD]; }
    if (t == 1023) offs[n] = run;
}

// MFMA GEMM: C[M][NC] = A @ B (BT16 = B^T [NC][128] bf16). A fp32 (cast in
// staging) or bf16. W32/W16 outputs, optional bias.
template <int NC, bool A32, bool W32, bool W16, bool BIAS>
__global__ __launch_bounds__(256) void k_gemm_mfma(
    const void* __restrict__ A,
    const unsigned short* __restrict__ BT16,
    const float* __restrict__ bias,
    float* __restrict__ C,
    unsigned short* __restrict__ C16, int M) {
    __shared__ unsigned short a_lds[64][136];  // +8 pad
    __shared__ unsigned short b_lds[64][136];
    int t = threadIdx.x;
    int rbase = blockIdx.x * 64;
    int cbase = blockIdx.y * 64;
    #pragma unroll
    for (int i = 0; i < 4; ++i) {
        int idx = t * 8 + i * 2048;
        int r = idx >> 7, k = idx & 127;
        if constexpr (A32) {
            const float* Af = (const float*)A;
            float4 f0 = make_float4(0.f, 0.f, 0.f, 0.f), f1 = f0;
            if (rbase + r < M) {
                f0 = *(const float4*)(Af + (size_t)(rbase + r) * 128 + k);
                f1 = *(const float4*)(Af + (size_t)(rbase + r) * 128 + k + 4);
            }
            uint4 v = make_uint4(pack2(f0.x, f0.y), pack2(f0.z, f0.w),
                                 pack2(f1.x, f1.y), pack2(f1.z, f1.w));
            *(uint4*)&a_lds[r][k] = v;
        } else {
            const unsigned short* Ah = (const unsigned short*)A;
            uint4 v = make_uint4(0u, 0u, 0u, 0u);
            if (rbase + r < M) v = *(const uint4*)(Ah + (size_t)(rbase + r) * 128 + k);
            *(uint4*)&a_lds[r][k] = v;
        }
    }
    #pragma unroll
    for (int i = 0; i < 4; ++i) {
        int idx = t * 8 + i * 2048;
        int r = idx >> 7, k = idx & 127;
        uint4 v = *(const uint4*)(BT16 + (size_t)(cbase + r) * 128 + k);
        *(uint4*)&b_lds[r][k] = v;
    }
    __syncthreads();
    int lane = t & 63, w = t >> 6;
    int lr = lane & 15, lk = (lane >> 4) * 8;
    f32x4 acc[4] = {f32x4{0.f, 0.f, 0.f, 0.f}, f32x4{0.f, 0.f, 0.f, 0.f},
                    f32x4{0.f, 0.f, 0.f, 0.f}, f32x4{0.f, 0.f, 0.f, 0.f}};
    #pragma unroll
    for (int kt = 0; kt < 4; ++kt) {
        short8 a = *(const short8*)&a_lds[w * 16 + lr][kt * 32 + lk];
        #pragma unroll
        for (int ct = 0; ct < 4; ++ct) {
            short8 b = *(const short8*)&b_lds[ct * 16 + lr][kt * 32 + lk];
            acc[ct] = __builtin_amdgcn_mfma_f32_16x16x32_bf16(a, b, acc[ct], 0, 0, 0);
        }
    }
    int rw = rbase + w * 16 + (lane >> 4) * 4;
    #pragma unroll
    for (int ct = 0; ct < 4; ++ct) {
        int col = cbase + ct * 16 + lr;
        float bv = 0.f;
        if constexpr (BIAS) bv = bias[col];
        #pragma unroll
        for (int j = 0; j < 4; ++j) {
            int r = rw + j;
            if (r < M) {
                float v = acc[ct][j] + bv;
                if constexpr (W32) C[(size_t)r * NC + col] = v;
                if constexpr (W16) C16[(size_t)r * NC + col] = f2bf(v);
            }
        }
    }
}

// Merged: CSR scatter + edge-attention matvec (blocks < fillBlocks, 16 lanes
// per edge -> wave reads 4 contiguous 256B rows = 1KB coalesced; MW rows in
// REGISTERS, no LDS -> zero bank conflicts) and layer-0 rowdot (rest).
__global__ __launch_bounds__(256) void k_fill_rd(
    const int* __restrict__ dst, const int* __restrict__ src,
    const int* __restrict__ offs, const int* __restrict__ rank,
    const float* __restrict__ eattr, const float* __restrict__ MW,
    const float* __restrict__ cvec,
    int* __restrict__ src_s, float* __restrict__ a_e_i, int E_,
    const float* __restrict__ X, const float* __restrict__ V,
    float* __restrict__ O, int M, int fillBlocks) {
    int t = threadIdx.x;
    if ((int)blockIdx.x < fillBlocks) {
        int lane = t & 63;
        int g = lane >> 4, j = lane & 15;          // 4 edges/wave, 16 lanes/edge
        // this lane's 4 MW rows (j*4..j*4+3) in registers (L2-hot, once)
        float4 m0a = *(const float4*)(MW + (j * 4 + 0) * 8);
        float4 m0b = *(const float4*)(MW + (j * 4 + 0) * 8 + 4);
        float4 m1a = *(const float4*)(MW + (j * 4 + 1) * 8);
        float4 m1b = *(const float4*)(MW + (j * 4 + 1) * 8 + 4);
        float4 m2a = *(const float4*)(MW + (j * 4 + 2) * 8);
        float4 m2b = *(const float4*)(MW + (j * 4 + 2) * 8 + 4);
        float4 m3a = *(const float4*)(MW + (j * 4 + 3) * 8);
        float4 m3b = *(const float4*)(MW + (j * 4 + 3) * 8 + 4);
        float4 cvv = make_float4(0.f, 0.f, 0.f, 0.f);
        if (j < 2) cvv = *(const float4*)(cvec + j * 4);
        int wv = (blockIdx.x * 256 + t) >> 6;
        int e = wv * 4 + g;
        if (e >= E_) return;
        int d = dst[e];                             // broadcast within group
        int pos = offs[d] + rank[e];
        float4 v = *(const float4*)(eattr + (size_t)e * 64 + j * 4);
        float acc[8];
        acc[0] = fmaf(v.x, m0a.x, fmaf(v.y, m1a.x, fmaf(v.z, m2a.x, v.w * m3a.x)));
        acc[1] = fmaf(v.x, m0a.y, fmaf(v.y, m1a.y, fmaf(v.z, m2a.y, v.w * m3a.y)));
        acc[2] = fmaf(v.x, m0a.z, fmaf(v.y, m1a.z, fmaf(v.z, m2a.z, v.w * m3a.z)));
        acc[3] = fmaf(v.x, m0a.w, fmaf(v.y, m1a.w, fmaf(v.z, m2a.w, v.w * m3a.w)));
        acc[4] = fmaf(v.x, m0b.x, fmaf(v.y, m1b.x, fmaf(v.z, m2b.x, v.w * m3b.x)));
        acc[5] = fmaf(v.x, m0b.y, fmaf(v.y, m1b.y, fmaf(v.z, m2b.y, v.w * m3b.y)));
        acc[6] = fmaf(v.x, m0b.z, fmaf(v.y, m1b.z, fmaf(v.z, m2b.z, v.w * m3b.z)));
        acc[7] = fmaf(v.x, m0b.w, fmaf(v.y, m1b.w, fmaf(v.z, m2b.w, v.w * m3b.w)));
        #pragma unroll
        for (int off = 1; off < 16; off <<= 1)
            #pragma unroll
            for (int q = 0; q < 8; ++q) acc[q] += __shfl_xor(acc[q], off);
        if (j < 2) {
            float4 o = make_float4(acc[j * 4 + 0] + cvv.x, acc[j * 4 + 1] + cvv.y,
                                   acc[j * 4 + 2] + cvv.z, acc[j * 4 + 3] + cvv.w);
            *(float4*)(a_e_i + (size_t)pos * 8 + j * 4) = o;
        } else if (j == 2) {
            src_s[pos] = src[e];
        }
    } else {
        __shared__ float v_lds[128][8];
        for (int idx = t; idx < 1024; idx += 256) v_lds[idx >> 3][idx & 7] = V[idx];
        __syncthreads();
        int row = (blockIdx.x - fillBlocks) * 256 + t;
        if (row >= M) return;
        float acc[8] = {};
        const float4* x4 = (const float4*)(X + (size_t)row * 128);
        for (int k4 = 0; k4 < 32; ++k4) {
            float4 xv = x4[k4];
            float xc[4] = {xv.x, xv.y, xv.z, xv.w};
            #pragma unroll
            for (int m = 0; m < 4; ++m)
                #pragma unroll
                for (int o = 0; o < 8; ++o) acc[o] = fmaf(xc[m], v_lds[k4 * 4 + m][o], acc[o]);
        }
        *(float4*)(O + (size_t)row * 8) = make_float4(acc[0], acc[1], acc[2], acc[3]);
        *(float4*)(O + (size_t)row * 8 + 4) = make_float4(acc[4], acc[5], acc[6], acc[7]);
    }
}

// Fused softmax+gather, one edge sweep, UNROLL-2 with independent chains
// (dual accumulators + pair-ahead src prefetch). Wave per node; lane l:
// head l>>4, channels (l&15)*8..+7, one uint4/edge. Shift-free softmax;
// self-loop edge logit = running mean; bias dropped (BN absorbs). No
// trailing block barrier — waves retire independently.
__global__ __launch_bounds__(256) void k_agg(
    const int* __restrict__ offs, const int* __restrict__ src_s,
    const float* __restrict__ a_sd, const float* __restrict__ a_e_i,
    const unsigned short* __restrict__ xh16,
    float* __restrict__ outb, int N_, int lsel) {
    int wid = (blockIdx.x * 256 + threadIdx.x) >> 6;
    int lane = threadIdx.x & 63;
    if (wid >= N_) return;
    int n = wid;
    int s0 = offs[n], s1 = offs[n + 1];
    int hsel = lane >> 4;
    int qoff = lsel * 4 + hsel;
    float ad = a_sd[(size_t)n * 8 + 4 + hsel];
    float acc[8] = {}, acc2[8] = {};
    float ssum = 0.f, ssum2 = 0.f, macc = 0.f;
    int idx = s0;
    int sa_n = 0, sb_n = 0;
    if (idx + 1 < s1) { sa_n = src_s[idx]; sb_n = src_s[idx + 1]; }
    for (; idx + 1 < s1; idx += 2) {
        int sa = sa_n, sb = sb_n;
        if (idx + 3 < s1) { sa_n = src_s[idx + 2]; sb_n = src_s[idx + 3]; }
        float aea = a_e_i[(size_t)idx * 8 + qoff];
        float aeb = a_e_i[(size_t)(idx + 1) * 8 + qoff];
        float asa = a_sd[(size_t)sa * 8 + hsel];
        float asb = a_sd[(size_t)sb * 8 + hsel];
        uint4 va = *(const uint4*)(xh16 + (size_t)sa * 512 + lane * 8);
        uint4 vb = *(const uint4*)(xh16 + (size_t)sb * 512 + lane * 8);
        macc += aea + aeb;
        float ra = asa + aea + ad;
        ra = ra >= 0.f ? ra : 0.2f * ra;
        float rb = asb + aeb + ad;
        rb = rb >= 0.f ? rb : 0.2f * rb;
        float exa = __expf(ra), exb = __expf(rb);
        ssum += exa;
        ssum2 += exb;
        float2 a0 = bf2(va.x), a1 = bf2(va.y), a2 = bf2(va.z), a3 = bf2(va.w);
        float2 b0 = bf2(vb.x), b1 = bf2(vb.y), b2 = bf2(vb.z), b3 = bf2(vb.w);
        acc[0] = fmaf(exa, a0.x, acc[0]);  acc[1] = fmaf(exa, a0.y, acc[1]);
        acc[2] = fmaf(exa, a1.x, acc[2]);  acc[3] = fmaf(exa, a1.y, acc[3]);
        acc[4] = fmaf(exa, a2.x, acc[4]);  acc[5] = fmaf(exa, a2.y, acc[5]);
        acc[6] = fmaf(exa, a3.x, acc[6]);  acc[7] = fmaf(exa, a3.y, acc[7]);
        acc2[0] = fmaf(exb, b0.x, acc2[0]); acc2[1] = fmaf(exb, b0.y, acc2[1]);
        acc2[2] = fmaf(exb, b1.x, acc2[2]); acc2[3] = fmaf(exb, b1.y, acc2[3]);
        acc2[4] = fmaf(exb, b2.x, acc2[4]); acc2[5] = fmaf(exb, b2.y, acc2[5]);
        acc2[6] = fmaf(exb, b3.x, acc2[6]); acc2[7] = fmaf(exb, b3.y, acc2[7]);
    }
    if (idx < s1) {   // tail edge
        int sn = src_s[idx];
        float ae = a_e_i[(size_t)idx * 8 + qoff];
        float as = a_sd[(size_t)sn * 8 + hsel];
        uint4 v = *(const uint4*)(xh16 + (size_t)sn * 512 + lane * 8);
        macc += ae;
        float raw = as + ae + ad;
        raw = raw >= 0.f ? raw : 0.2f * raw;
        float ex = __expf(raw);
        ssum += ex;
        float2 p0 = bf2(v.x), p1 = bf2(v.y), p2 = bf2(v.z), p3 = bf2(v.w);
        acc[0] = fmaf(ex, p0.x, acc[0]); acc[1] = fmaf(ex, p0.y, acc[1]);
        acc[2] = fmaf(ex, p1.x, acc[2]); acc[3] = fmaf(ex, p1.y, acc[3]);
        acc[4] = fmaf(ex, p2.x, acc[4]); acc[5] = fmaf(ex, p2.y, acc[5]);
        acc[6] = fmaf(ex, p3.x, acc[6]); acc[7] = fmaf(ex, p3.y, acc[7]);
    }
    ssum += ssum2;
    #pragma unroll
    for (int q = 0; q < 8; ++q) acc[q] += acc2[q];
    {   // self loop: edge-feature logit = mean of in-edge logits (fill='mean')
        float dg = (float)max(s1 - s0, 1);
        float ae = macc / dg;
        float as = a_sd[(size_t)n * 8 + hsel];
        float raw = as + ae + ad;
        raw = raw >= 0.f ? raw : 0.2f * raw;
        float ex = __expf(raw);
        ssum += ex;
        uint4 v = *(const uint4*)(xh16 + (size_t)n * 512 + lane * 8);
        float2 p0 = bf2(v.x), p1 = bf2(v.y), p2 = bf2(v.z), p3 = bf2(v.w);
        acc[0] = fmaf(ex, p0.x, acc[0]); acc[1] = fmaf(ex, p0.y, acc[1]);
        acc[2] = fmaf(ex, p1.x, acc[2]); acc[3] = fmaf(ex, p1.y, acc[3]);
        acc[4] = fmaf(ex, p2.x, acc[4]); acc[5] = fmaf(ex, p2.y, acc[5]);
        acc[6] = fmaf(ex, p3.x, acc[6]); acc[7] = fmaf(ex, p3.y, acc[7]);
    }
    float inv = 0.25f / (ssum + 1e-16f);   // head-mean folded in
    #pragma unroll
    for (int q = 0; q < 8; ++q) acc[q] *= inv;
    // sum across the 4 head groups (lanes l, l^16, l^32, l^48)
    #pragma unroll
    for (int off = 16; off <= 32; off <<= 1)
        #pragma unroll
        for (int q = 0; q < 8; ++q) acc[q] += __shfl_xor(acc[q], off);
    if (lane < 16) {
        float* orow = outb + (size_t)n * 128 + lane * 8;
        *(float4*)orow = make_float4(acc[0], acc[1], acc[2], acc[3]);
        *(float4*)(orow + 4) = make_float4(acc[4], acc[5], acc[6], acc[7]);
    }
}

__global__ __launch_bounds__(128) void k_bnstats(const float* __restrict__ outb,
                                                 float* __restrict__ bnsum,
                                                 float* __restrict__ bnsumsq, int N_) {
    int c = threadIdx.x;
    float s = 0.f, s2 = 0.f;
    for (int r = blockIdx.x; r < N_; r += gridDim.x) {
        float v = outb[(size_t)r * 128 + c];
        s += v;
        s2 = fmaf(v, v, s2);
    }
    atomicAdd(&bnsum[c], s);
    atomicAdd(&bnsumsq[c], s2);
}

// BN apply + residual + relu; optionally fused next-layer a_sd rowdot.
template <bool DOROW>
__global__ __launch_bounds__(256) void k_bn_apply_rd(
    const float* __restrict__ outb, const float* __restrict__ bnsum,
    const float* __restrict__ bnsumsq, const float* __restrict__ gamma,
    const float* __restrict__ beta, const float* __restrict__ wa,
    float* __restrict__ h, unsigned short* __restrict__ h16,
    float* __restrict__ a_sd, int N_) {
    __shared__ float wlds[128][8];
    int t = threadIdx.x;
    if constexpr (DOROW) {
        for (int i = t; i < 1024; i += 256) wlds[i >> 3][i & 7] = wa[i];
        __syncthreads();
    }
    int wid = (blockIdx.x * 256 + t) >> 6;
    int lane = t & 63;
    if (wid >= N_) return;
    int n = wid;
    float invN = 1.0f / (float)N_;
    int c0 = lane, c1 = lane + 64;
    float mu0 = bnsum[c0] * invN, mu1 = bnsum[c1] * invN;
    float g0 = rsqrtf(bnsumsq[c0] * invN - mu0 * mu0 + 1e-5f) * gamma[c0];
    float g1 = rsqrtf(bnsumsq[c1] * invN - mu1 * mu1 + 1e-5f) * gamma[c1];
    float o0 = outb[(size_t)n * 128 + c0], o1 = outb[(size_t)n * 128 + c1];
    float v0 = (o0 - mu0) * g0 + beta[c0];
    float v1 = (o1 - mu1) * g1 + beta[c1];
    float nh0 = h[(size_t)n * 128 + c0] + fmaxf(v0, 0.f);
    float nh1 = h[(size_t)n * 128 + c1] + fmaxf(v1, 0.f);
    h[(size_t)n * 128 + c0] = nh0;
    h[(size_t)n * 128 + c1] = nh1;
    h16[(size_t)n * 128 + c0] = f2bf(nh0);
    h16[(size_t)n * 128 + c1] = f2bf(nh1);
    if constexpr (DOROW) {
        float p[8];
        #pragma unroll
        for (int m = 0; m < 8; ++m)
            p[m] = fmaf(nh0, wlds[c0][m], nh1 * wlds[c1][m]);
        #pragma unroll
        for (int off = 1; off < 64; off <<= 1)
            #pragma unroll
            for (int m = 0; m < 8; ++m) p[m] += __shfl_xor(p[m], off);
        if (lane == 0) {
            *(float4*)(a_sd + (size_t)n * 8) = make_float4(p[0], p[1], p[2], p[3]);
            *(float4*)(a_sd + (size_t)n * 8 + 4) = make_float4(p[4], p[5], p[6], p[7]);
        }
    }
}

extern "C" void kernel_launch(void* const* d_in, const int* in_sizes, int n_in,
                              void* d_out, int out_size, void* d_ws, size_t ws_size,
                              hipStream_t stream) {
    const float* x = (const float*)d_in[0];
    const int* ei = (const int*)d_in[1];
    const float* eattr = (const float*)d_in[2];
    const float* encW = (const float*)d_in[4];
    const float* encb = (const float*)d_in[5];
    const float* eencW = (const float*)d_in[6];
    const float* eencb = (const float*)d_in[7];
    const float* W = (const float*)d_in[8];
    const float* We = (const float*)d_in[9];
    const float* att_src = (const float*)d_in[10];
    const float* att_dst = (const float*)d_in[11];
    const float* att_edge = (const float*)d_in[12];
    const float* gamma = (const float*)d_in[14];
    const float* beta = (const float*)d_in[15];

    const int N = in_sizes[0] / 128;
    const int E = in_sizes[1] / 2;
    const int* srcIdx = ei;
    const int* dstIdx = ei + E;
    float* h = (float*)d_out;

    char* wbase = (char*)d_ws;
    size_t off = 0;
    auto alloc = [&](size_t bytes) -> void* {
        void* p = wbase + off;
        off = (off + bytes + 255) & ~(size_t)255;
        return p;
    };
    unsigned short* encWT16 = (unsigned short*)alloc((size_t)128 * 128 * 2);
    unsigned short* WT16 = (unsigned short*)alloc((size_t)2 * 512 * 128 * 2);
    float* we_att = (float*)alloc((size_t)128 * 8 * 4);
    float* wa_sd = (float*)alloc((size_t)2 * 128 * 8 * 4);
    float* MW = (float*)alloc((size_t)64 * 8 * 4);
    float* cvec = (float*)alloc((size_t)8 * 4);
    int* deg = (int*)alloc((size_t)N * DEGPAD * 4);  // padded counters
    int* rank = (int*)alloc((size_t)E * 4);
    int* offs = (int*)alloc((size_t)(N + 1) * 4);
    int* src_s = (int*)alloc((size_t)E * 4);
    float* a_e_i = (float*)alloc((size_t)E * 8 * 4);   // interleaved [pos][8]
    float* a_sd = (float*)alloc((size_t)N * 8 * 4);
    unsigned short* h16 = (unsigned short*)alloc((size_t)N * 128 * 2);
    unsigned short* xh16 = (unsigned short*)alloc((size_t)N * 512 * 2);  // [N][512]
    float* outb = (float*)alloc((size_t)N * 128 * 4);
    float* bnsum = (float*)alloc((size_t)4 * 128 * 4);
    float* bnsumsq = bnsum + 2 * 128;
    (void)ws_size; (void)n_in; (void)out_size;

    hipMemsetAsync(deg, 0, (size_t)N * DEGPAD * 4, stream);
    hipMemsetAsync(bnsum, 0, (size_t)4 * 128 * 4, stream);

    int eb = (E + 255) / 256;
    // prep + attention collapse + degree histogram w/ rank capture (merged)
    k_misc1<<<588 + eb, 256, 0, stream>>>(encW, W, We, att_src, att_dst, att_edge,
                                          dstIdx, encWT16, WT16, we_att, wa_sd,
                                          deg, rank, E);
    // scan (block 0) + MW collapse (block 1)
    k_scan_mw<<<2, 1024, 0, stream>>>(deg, offs, N, eencW, eencb, we_att, MW, cvec);

    // node encoder (MFMA, fp32 A cast in staging): h = x @ enc_W + enc_b
    k_gemm_mfma<128, true, true, true, true>
        <<<dim3((N + 63) / 64, 2), 256, 0, stream>>>(x, encWT16, encb, h, h16, N);

    // CSR scatter (16 lanes/edge, coalesced, MW in regs) + layer-0 rowdot
    int fb = (E + 15) / 16;     // 16 edges per block (4 waves x 4 edges)
    int rb = (N + 255) / 256;
    k_fill_rd<<<fb + rb, 256, 0, stream>>>(dstIdx, srcIdx, offs, rank, eattr, MW,
                                           cvec, src_s, a_e_i, E, h, wa_sd, a_sd,
                                           N, fb);

    int ab = (N * 64 + 255) / 256;
    for (int l = 0; l < 2; ++l) {
        k_gemm_mfma<512, false, false, true, false>
            <<<dim3((N + 63) / 64, 8), 256, 0, stream>>>(
                h16, WT16 + (size_t)l * 512 * 128, nullptr, nullptr, xh16, N);
        k_agg<<<ab, 256, 0, stream>>>(
            offs, src_s, a_sd, a_e_i, xh16, outb, N, l);
        k_bnstats<<<256, 128, 0, stream>>>(outb, bnsum + l * 128, bnsumsq + l * 128, N);
        if (l == 0) {
            k_bn_apply_rd<true><<<ab, 256, 0, stream>>>(
                outb, bnsum, bnsumsq, gamma, beta, wa_sd + 1024, h, h16, a_sd, N);
        } else {
            k_bn_apply_rd<false><<<ab, 256, 0, stream>>>(
                outb, bnsum + 128, bnsumsq + 128, gamma + 128, beta + 128,
                nullptr, h, h16, nullptr, N);
        }
    }
}

// Round 16
// 236.653 us; speedup vs baseline: 1.2294x; 1.2294x over previous
//
#include <hip/hip_runtime.h>
#include <hip/hip_bf16.h>

typedef __attribute__((ext_vector_type(8))) short short8;
typedef __attribute__((ext_vector_type(4))) float f32x4;

#define DEGPAD 16   // one counter per 64B line: kills atomic line-contention

__device__ __forceinline__ unsigned short f2bf(float x) {
    unsigned int u = __float_as_uint(x);
    u += 0x7fffu + ((u >> 16) & 1u);   // round-to-nearest-even
    return (unsigned short)(u >> 16);
}

__device__ __forceinline__ unsigned int pack2(float a, float b) {
    return (unsigned int)f2bf(a) | ((unsigned int)f2bf(b) << 16);
}

__device__ __forceinline__ float2 bf2(unsigned int u) {
    float lo = __uint_as_float(u << 16);
    float hi = __uint_as_float(u & 0xffff0000u);
    return make_float2(lo, hi);
}

// Merged: weight prep (blocks 0..575) + attention collapse & BN-stat zeroing
// (576..587) + degree histogram with RANK capture (588..).
__global__ __launch_bounds__(256) void k_misc1(
    const float* __restrict__ encW, const float* __restrict__ W,
    const float* __restrict__ We, const float* __restrict__ att_src,
    const float* __restrict__ att_dst, const float* __restrict__ att_edge,
    const int* __restrict__ dst,
    unsigned short* __restrict__ encWT16, unsigned short* __restrict__ WT16,
    float* __restrict__ we_att, float* __restrict__ wa_sd,
    int* __restrict__ deg, int* __restrict__ rank,
    float* __restrict__ bnz, int E_) {
    int b = blockIdx.x, t = threadIdx.x;
    if (b < 576) {
        int o = b * 256 + t;
        if (o < 16384) {
            int c = o >> 7, k = o & 127;
            encWT16[o] = f2bf(encW[k * 128 + c]);
        } else {
            int o2 = o - 16384;
            int l = o2 >> 16, r = o2 & 65535;
            int c = r >> 7, k = r & 127;
            WT16[o2] = f2bf(W[((size_t)l * 128 + k) * 512 + c]);
        }
    } else if (b < 588) {
        int o = (b - 576) * 256 + t;
        if (b < 578) bnz[o] = 0.f;   // zero bnsum/bnsumsq (512 floats), no memset
        if (o < 1024) {
            int k = o >> 3, lh = o & 7, l = lh >> 2, hh = lh & 3;
            const float* wrow = We + ((size_t)(l * 128 + k)) * 512 + hh * 128;
            const float* av = att_edge + (l * 4 + hh) * 128;
            float s = 0.f;
            #pragma unroll 8
            for (int c = 0; c < 128; ++c) s = fmaf(wrow[c], av[c], s);
            we_att[o] = s;
        } else if (o < 3072) {
            int o2 = o - 1024;
            int l = o2 >> 10, r = o2 & 1023, k = r >> 3, m = r & 7, hh = m & 3;
            const float* wrow = W + ((size_t)(l * 128 + k)) * 512 + hh * 128;
            const float* av = (m < 4 ? att_src : att_dst) + (l * 4 + hh) * 128;
            float s = 0.f;
            #pragma unroll 8
            for (int c = 0; c < 128; ++c) s = fmaf(wrow[c], av[c], s);
            wa_sd[o2] = s;
        }
    } else {
        int e = (b - 588) * 256 + t;
        if (e < E_) rank[e] = atomicAdd(&deg[(size_t)dst[e] * DEGPAD], 1);
    }
}

// Block 0: exclusive scan of padded deg -> offs.  Block 1: MW/cvec collapse.
__global__ __launch_bounds__(1024) void k_scan_mw(
    const int* __restrict__ deg, int* __restrict__ offs, int n,
    const float* __restrict__ eencW, const float* __restrict__ eencb,
    const float* __restrict__ we_att,
    float* __restrict__ MW, float* __restrict__ cvec) {
    int t = threadIdx.x;
    if (blockIdx.x == 1) {
        if (t < 512) {
            int k = t >> 3, q = t & 7;
            float s = 0.f;
            #pragma unroll 8
            for (int c = 0; c < 128; ++c) s = fmaf(eencW[k * 128 + c], we_att[c * 8 + q], s);
            MW[t] = s;
        } else if (t < 520) {
            int q = t - 512;
            float s = 0.f;
            #pragma unroll 8
            for (int c = 0; c < 128; ++c) s = fmaf(eencb[c], we_att[c * 8 + q], s);
            cvec[q] = s;
        }
        return;
    }
    __shared__ int part[1024];
    int per = (n + 1023) / 1024;
    int beg = t * per, end = min(beg + per, n);
    int s = 0;
    for (int i = beg; i < end; ++i) s += deg[(size_t)i * DEGPAD];
    part[t] = s;
    __syncthreads();
    for (int off = 1; off < 1024; off <<= 1) {
        int v = (t >= off) ? part[t - off] : 0;
        __syncthreads();
        part[t] += v;
        __syncthreads();
    }
    int run = (t == 0) ? 0 : part[t - 1];
    for (int i = beg; i < end; ++i) { offs[i] = run; run += deg[(size_t)i * DEGPAD]; }
    if (t == 1023) offs[n] = run;
}

// MFMA GEMM: C[M][NC] = A @ B (BT16 = B^T [NC][128] bf16). A fp32 (cast in
// staging) or bf16. W32/W16 outputs, optional bias.
template <int NC, bool A32, bool W32, bool W16, bool BIAS>
__global__ __launch_bounds__(256) void k_gemm_mfma(
    const void* __restrict__ A,
    const unsigned short* __restrict__ BT16,
    const float* __restrict__ bias,
    float* __restrict__ C,
    unsigned short* __restrict__ C16, int M) {
    __shared__ unsigned short a_lds[64][136];  // +8 pad
    __shared__ unsigned short b_lds[64][136];
    int t = threadIdx.x;
    int rbase = blockIdx.x * 64;
    int cbase = blockIdx.y * 64;
    #pragma unroll
    for (int i = 0; i < 4; ++i) {
        int idx = t * 8 + i * 2048;
        int r = idx >> 7, k = idx & 127;
        if constexpr (A32) {
            const float* Af = (const float*)A;
            float4 f0 = make_float4(0.f, 0.f, 0.f, 0.f), f1 = f0;
            if (rbase + r < M) {
                f0 = *(const float4*)(Af + (size_t)(rbase + r) * 128 + k);
                f1 = *(const float4*)(Af + (size_t)(rbase + r) * 128 + k + 4);
            }
            uint4 v = make_uint4(pack2(f0.x, f0.y), pack2(f0.z, f0.w),
                                 pack2(f1.x, f1.y), pack2(f1.z, f1.w));
            *(uint4*)&a_lds[r][k] = v;
        } else {
            const unsigned short* Ah = (const unsigned short*)A;
            uint4 v = make_uint4(0u, 0u, 0u, 0u);
            if (rbase + r < M) v = *(const uint4*)(Ah + (size_t)(rbase + r) * 128 + k);
            *(uint4*)&a_lds[r][k] = v;
        }
    }
    #pragma unroll
    for (int i = 0; i < 4; ++i) {
        int idx = t * 8 + i * 2048;
        int r = idx >> 7, k = idx & 127;
        uint4 v = *(const uint4*)(BT16 + (size_t)(cbase + r) * 128 + k);
        *(uint4*)&b_lds[r][k] = v;
    }
    __syncthreads();
    int lane = t & 63, w = t >> 6;
    int lr = lane & 15, lk = (lane >> 4) * 8;
    f32x4 acc[4] = {f32x4{0.f, 0.f, 0.f, 0.f}, f32x4{0.f, 0.f, 0.f, 0.f},
                    f32x4{0.f, 0.f, 0.f, 0.f}, f32x4{0.f, 0.f, 0.f, 0.f}};
    #pragma unroll
    for (int kt = 0; kt < 4; ++kt) {
        short8 a = *(const short8*)&a_lds[w * 16 + lr][kt * 32 + lk];
        #pragma unroll
        for (int ct = 0; ct < 4; ++ct) {
            short8 b = *(const short8*)&b_lds[ct * 16 + lr][kt * 32 + lk];
            acc[ct] = __builtin_amdgcn_mfma_f32_16x16x32_bf16(a, b, acc[ct], 0, 0, 0);
        }
    }
    int rw = rbase + w * 16 + (lane >> 4) * 4;
    #pragma unroll
    for (int ct = 0; ct < 4; ++ct) {
        int col = cbase + ct * 16 + lr;
        float bv = 0.f;
        if constexpr (BIAS) bv = bias[col];
        #pragma unroll
        for (int j = 0; j < 4; ++j) {
            int r = rw + j;
            if (r < M) {
                float v = acc[ct][j] + bv;
                if constexpr (W32) C[(size_t)r * NC + col] = v;
                if constexpr (W16) C16[(size_t)r * NC + col] = f2bf(v);
            }
        }
    }
}

// Merged: CSR scatter + edge-attention matvec (blocks < fillBlocks; row per
// thread, mw in LDS read at UNIFORM addresses -> broadcast, conflict-free;
// measured-best round-13 form) and layer-0 rowdot a_sd (remaining blocks).
// Slot = offs[dst] + rank -> no atomics.
__global__ __launch_bounds__(256) void k_fill_rd(
    const int* __restrict__ dst, const int* __restrict__ src,
    const int* __restrict__ offs, const int* __restrict__ rank,
    const float* __restrict__ eattr, const float* __restrict__ MW,
    const float* __restrict__ cvec,
    int* __restrict__ src_s, float* __restrict__ a_e_i, int E_,
    const float* __restrict__ X, const float* __restrict__ V,
    float* __restrict__ O, int M, int fillBlocks) {
    int t = threadIdx.x;
    if ((int)blockIdx.x < fillBlocks) {
        __shared__ float mw[64][8];
        __shared__ float cv[8];
        for (int i = t; i < 512; i += 256) mw[i >> 3][i & 7] = MW[i];
        if (t < 8) cv[t] = cvec[t];
        __syncthreads();
        int e = blockIdx.x * 256 + t;
        if (e >= E_) return;
        int d = dst[e];
        int pos = offs[d] + rank[e];
        float acc[8];
        #pragma unroll
        for (int q = 0; q < 8; ++q) acc[q] = cv[q];
        const float4* r = (const float4*)(eattr + (size_t)e * 64);
        #pragma unroll 4
        for (int k4 = 0; k4 < 16; ++k4) {
            float4 v = r[k4];
            float xc[4] = {v.x, v.y, v.z, v.w};
            #pragma unroll
            for (int m = 0; m < 4; ++m)
                #pragma unroll
                for (int q = 0; q < 8; ++q)
                    acc[q] = fmaf(xc[m], mw[k4 * 4 + m][q], acc[q]);
        }
        src_s[pos] = src[e];
        *(float4*)(a_e_i + (size_t)pos * 8) = make_float4(acc[0], acc[1], acc[2], acc[3]);
        *(float4*)(a_e_i + (size_t)pos * 8 + 4) = make_float4(acc[4], acc[5], acc[6], acc[7]);
    } else {
        __shared__ float v_lds[128][8];
        for (int idx = t; idx < 1024; idx += 256) v_lds[idx >> 3][idx & 7] = V[idx];
        __syncthreads();
        int row = (blockIdx.x - fillBlocks) * 256 + t;
        if (row >= M) return;
        float acc[8] = {};
        const float4* x4 = (const float4*)(X + (size_t)row * 128);
        for (int k4 = 0; k4 < 32; ++k4) {
            float4 xv = x4[k4];
            float xc[4] = {xv.x, xv.y, xv.z, xv.w};
            #pragma unroll
            for (int m = 0; m < 4; ++m)
                #pragma unroll
                for (int o = 0; o < 8; ++o) acc[o] = fmaf(xc[m], v_lds[k4 * 4 + m][o], acc[o]);
        }
        *(float4*)(O + (size_t)row * 8) = make_float4(acc[0], acc[1], acc[2], acc[3]);
        *(float4*)(O + (size_t)row * 8 + 4) = make_float4(acc[4], acc[5], acc[6], acc[7]);
    }
}

// Fused softmax+gather, one edge sweep, UNROLL-2 with independent chains
// (dual accumulators + pair-ahead src prefetch). Wave per node; lane l:
// head l>>4, channels (l&15)*8..+7, one uint4/edge. Shift-free softmax;
// self-loop edge logit = running mean; bias dropped (BN absorbs). No
// trailing block barrier — waves retire independently.
__global__ __launch_bounds__(256) void k_agg(
    const int* __restrict__ offs, const int* __restrict__ src_s,
    const float* __restrict__ a_sd, const float* __restrict__ a_e_i,
    const unsigned short* __restrict__ xh16,
    float* __restrict__ outb, int N_, int lsel) {
    int wid = (blockIdx.x * 256 + threadIdx.x) >> 6;
    int lane = threadIdx.x & 63;
    if (wid >= N_) return;
    int n = wid;
    int s0 = offs[n], s1 = offs[n + 1];
    int hsel = lane >> 4;
    int qoff = lsel * 4 + hsel;
    float ad = a_sd[(size_t)n * 8 + 4 + hsel];
    float acc[8] = {}, acc2[8] = {};
    float ssum = 0.f, ssum2 = 0.f, macc = 0.f;
    int idx = s0;
    int sa_n = 0, sb_n = 0;
    if (idx + 1 < s1) { sa_n = src_s[idx]; sb_n = src_s[idx + 1]; }
    for (; idx + 1 < s1; idx += 2) {
        int sa = sa_n, sb = sb_n;
        if (idx + 3 < s1) { sa_n = src_s[idx + 2]; sb_n = src_s[idx + 3]; }
        float aea = a_e_i[(size_t)idx * 8 + qoff];
        float aeb = a_e_i[(size_t)(idx + 1) * 8 + qoff];
        float asa = a_sd[(size_t)sa * 8 + hsel];
        float asb = a_sd[(size_t)sb * 8 + hsel];
        uint4 va = *(const uint4*)(xh16 + (size_t)sa * 512 + lane * 8);
        uint4 vb = *(const uint4*)(xh16 + (size_t)sb * 512 + lane * 8);
        macc += aea + aeb;
        float ra = asa + aea + ad;
        ra = ra >= 0.f ? ra : 0.2f * ra;
        float rb = asb + aeb + ad;
        rb = rb >= 0.f ? rb : 0.2f * rb;
        float exa = __expf(ra), exb = __expf(rb);
        ssum += exa;
        ssum2 += exb;
        float2 a0 = bf2(va.x), a1 = bf2(va.y), a2 = bf2(va.z), a3 = bf2(va.w);
        float2 b0 = bf2(vb.x), b1 = bf2(vb.y), b2 = bf2(vb.z), b3 = bf2(vb.w);
        acc[0] = fmaf(exa, a0.x, acc[0]);  acc[1] = fmaf(exa, a0.y, acc[1]);
        acc[2] = fmaf(exa, a1.x, acc[2]);  acc[3] = fmaf(exa, a1.y, acc[3]);
        acc[4] = fmaf(exa, a2.x, acc[4]);  acc[5] = fmaf(exa, a2.y, acc[5]);
        acc[6] = fmaf(exa, a3.x, acc[6]);  acc[7] = fmaf(exa, a3.y, acc[7]);
        acc2[0] = fmaf(exb, b0.x, acc2[0]); acc2[1] = fmaf(exb, b0.y, acc2[1]);
        acc2[2] = fmaf(exb, b1.x, acc2[2]); acc2[3] = fmaf(exb, b1.y, acc2[3]);
        acc2[4] = fmaf(exb, b2.x, acc2[4]); acc2[5] = fmaf(exb, b2.y, acc2[5]);
        acc2[6] = fmaf(exb, b3.x, acc2[6]); acc2[7] = fmaf(exb, b3.y, acc2[7]);
    }
    if (idx < s1) {   // tail edge
        int sn = src_s[idx];
        float ae = a_e_i[(size_t)idx * 8 + qoff];
        float as = a_sd[(size_t)sn * 8 + hsel];
        uint4 v = *(const uint4*)(xh16 + (size_t)sn * 512 + lane * 8);
        macc += ae;
        float raw = as + ae + ad;
        raw = raw >= 0.f ? raw : 0.2f * raw;
        float ex = __expf(raw);
        ssum += ex;
        float2 p0 = bf2(v.x), p1 = bf2(v.y), p2 = bf2(v.z), p3 = bf2(v.w);
        acc[0] = fmaf(ex, p0.x, acc[0]); acc[1] = fmaf(ex, p0.y, acc[1]);
        acc[2] = fmaf(ex, p1.x, acc[2]); acc[3] = fmaf(ex, p1.y, acc[3]);
        acc[4] = fmaf(ex, p2.x, acc[4]); acc[5] = fmaf(ex, p2.y, acc[5]);
        acc[6] = fmaf(ex, p3.x, acc[6]); acc[7] = fmaf(ex, p3.y, acc[7]);
    }
    ssum += ssum2;
    #pragma unroll
    for (int q = 0; q < 8; ++q) acc[q] += acc2[q];
    {   // self loop: edge-feature logit = mean of in-edge logits (fill='mean')
        float dg = (float)max(s1 - s0, 1);
        float ae = macc / dg;
        float as = a_sd[(size_t)n * 8 + hsel];
        float raw = as + ae + ad;
        raw = raw >= 0.f ? raw : 0.2f * raw;
        float ex = __expf(raw);
        ssum += ex;
        uint4 v = *(const uint4*)(xh16 + (size_t)n * 512 + lane * 8);
        float2 p0 = bf2(v.x), p1 = bf2(v.y), p2 = bf2(v.z), p3 = bf2(v.w);
        acc[0] = fmaf(ex, p0.x, acc[0]); acc[1] = fmaf(ex, p0.y, acc[1]);
        acc[2] = fmaf(ex, p1.x, acc[2]); acc[3] = fmaf(ex, p1.y, acc[3]);
        acc[4] = fmaf(ex, p2.x, acc[4]); acc[5] = fmaf(ex, p2.y, acc[5]);
        acc[6] = fmaf(ex, p3.x, acc[6]); acc[7] = fmaf(ex, p3.y, acc[7]);
    }
    float inv = 0.25f / (ssum + 1e-16f);   // head-mean folded in
    #pragma unroll
    for (int q = 0; q < 8; ++q) acc[q] *= inv;
    // sum across the 4 head groups (lanes l, l^16, l^32, l^48)
    #pragma unroll
    for (int off = 16; off <= 32; off <<= 1)
        #pragma unroll
        for (int q = 0; q < 8; ++q) acc[q] += __shfl_xor(acc[q], off);
    if (lane < 16) {
        float* orow = outb + (size_t)n * 128 + lane * 8;
        *(float4*)orow = make_float4(acc[0], acc[1], acc[2], acc[3]);
        *(float4*)(orow + 4) = make_float4(acc[4], acc[5], acc[6], acc[7]);
    }
}

__global__ __launch_bounds__(128) void k_bnstats(const float* __restrict__ outb,
                                                 float* __restrict__ bnsum,
                                                 float* __restrict__ bnsumsq, int N_) {
    int c = threadIdx.x;
    float s = 0.f, s2 = 0.f;
    for (int r = blockIdx.x; r < N_; r += gridDim.x) {
        float v = outb[(size_t)r * 128 + c];
        s += v;
        s2 = fmaf(v, v, s2);
    }
    atomicAdd(&bnsum[c], s);
    atomicAdd(&bnsumsq[c], s2);
}

// BN apply + residual + relu; optionally fused next-layer a_sd rowdot.
template <bool DOROW>
__global__ __launch_bounds__(256) void k_bn_apply_rd(
    const float* __restrict__ outb, const float* __restrict__ bnsum,
    const float* __restrict__ bnsumsq, const float* __restrict__ gamma,
    const float* __restrict__ beta, const float* __restrict__ wa,
    float* __restrict__ h, unsigned short* __restrict__ h16,
    float* __restrict__ a_sd, int N_) {
    __shared__ float wlds[128][8];
    int t = threadIdx.x;
    if constexpr (DOROW) {
        for (int i = t; i < 1024; i += 256) wlds[i >> 3][i & 7] = wa[i];
        __syncthreads();
    }
    int wid = (blockIdx.x * 256 + t) >> 6;
    int lane = t & 63;
    if (wid >= N_) return;
    int n = wid;
    float invN = 1.0f / (float)N_;
    int c0 = lane, c1 = lane + 64;
    float mu0 = bnsum[c0] * invN, mu1 = bnsum[c1] * invN;
    float g0 = rsqrtf(bnsumsq[c0] * invN - mu0 * mu0 + 1e-5f) * gamma[c0];
    float g1 = rsqrtf(bnsumsq[c1] * invN - mu1 * mu1 + 1e-5f) * gamma[c1];
    float o0 = outb[(size_t)n * 128 + c0], o1 = outb[(size_t)n * 128 + c1];
    float v0 = (o0 - mu0) * g0 + beta[c0];
    float v1 = (o1 - mu1) * g1 + beta[c1];
    float nh0 = h[(size_t)n * 128 + c0] + fmaxf(v0, 0.f);
    float nh1 = h[(size_t)n * 128 + c1] + fmaxf(v1, 0.f);
    h[(size_t)n * 128 + c0] = nh0;
    h[(size_t)n * 128 + c1] = nh1;
    h16[(size_t)n * 128 + c0] = f2bf(nh0);
    h16[(size_t)n * 128 + c1] = f2bf(nh1);
    if constexpr (DOROW) {
        float p[8];
        #pragma unroll
        for (int m = 0; m < 8; ++m)
            p[m] = fmaf(nh0, wlds[c0][m], nh1 * wlds[c1][m]);
        #pragma unroll
        for (int off = 1; off < 64; off <<= 1)
            #pragma unroll
            for (int m = 0; m < 8; ++m) p[m] += __shfl_xor(p[m], off);
        if (lane == 0) {
            *(float4*)(a_sd + (size_t)n * 8) = make_float4(p[0], p[1], p[2], p[3]);
            *(float4*)(a_sd + (size_t)n * 8 + 4) = make_float4(p[4], p[5], p[6], p[7]);
        }
    }
}

extern "C" void kernel_launch(void* const* d_in, const int* in_sizes, int n_in,
                              void* d_out, int out_size, void* d_ws, size_t ws_size,
                              hipStream_t stream) {
    const float* x = (const float*)d_in[0];
    const int* ei = (const int*)d_in[1];
    const float* eattr = (const float*)d_in[2];
    const float* encW = (const float*)d_in[4];
    const float* encb = (const float*)d_in[5];
    const float* eencW = (const float*)d_in[6];
    const float* eencb = (const float*)d_in[7];
    const float* W = (const float*)d_in[8];
    const float* We = (const float*)d_in[9];
    const float* att_src = (const float*)d_in[10];
    const float* att_dst = (const float*)d_in[11];
    const float* att_edge = (const float*)d_in[12];
    const float* gamma = (const float*)d_in[14];
    const float* beta = (const float*)d_in[15];

    const int N = in_sizes[0] / 128;
    const int E = in_sizes[1] / 2;
    const int* srcIdx = ei;
    const int* dstIdx = ei + E;
    float* h = (float*)d_out;

    char* wbase = (char*)d_ws;
    size_t off = 0;
    auto alloc = [&](size_t bytes) -> void* {
        void* p = wbase + off;
        off = (off + bytes + 255) & ~(size_t)255;
        return p;
    };
    unsigned short* encWT16 = (unsigned short*)alloc((size_t)128 * 128 * 2);
    unsigned short* WT16 = (unsigned short*)alloc((size_t)2 * 512 * 128 * 2);
    float* we_att = (float*)alloc((size_t)128 * 8 * 4);
    float* wa_sd = (float*)alloc((size_t)2 * 128 * 8 * 4);
    float* MW = (float*)alloc((size_t)64 * 8 * 4);
    float* cvec = (float*)alloc((size_t)8 * 4);
    int* deg = (int*)alloc((size_t)N * DEGPAD * 4);  // padded counters
    int* rank = (int*)alloc((size_t)E * 4);
    int* offs = (int*)alloc((size_t)(N + 1) * 4);
    int* src_s = (int*)alloc((size_t)E * 4);
    float* a_e_i = (float*)alloc((size_t)E * 8 * 4);   // interleaved [pos][8]
    float* a_sd = (float*)alloc((size_t)N * 8 * 4);
    unsigned short* h16 = (unsigned short*)alloc((size_t)N * 128 * 2);
    unsigned short* xh16 = (unsigned short*)alloc((size_t)N * 512 * 2);  // [N][512]
    float* outb = (float*)alloc((size_t)N * 128 * 4);
    float* bnsum = (float*)alloc((size_t)4 * 128 * 4);
    float* bnsumsq = bnsum + 2 * 128;
    (void)ws_size; (void)n_in; (void)out_size;

    // single memset: deg only (bnsum zeroed inside k_misc1)
    hipMemsetAsync(deg, 0, (size_t)N * DEGPAD * 4, stream);

    int eb = (E + 255) / 256;
    // prep + attention collapse + bn zero + degree histogram w/ rank capture
    k_misc1<<<588 + eb, 256, 0, stream>>>(encW, W, We, att_src, att_dst, att_edge,
                                          dstIdx, encWT16, WT16, we_att, wa_sd,
                                          deg, rank, bnsum, E);
    // scan (block 0) + MW collapse (block 1)
    k_scan_mw<<<2, 1024, 0, stream>>>(deg, offs, N, eencW, eencb, we_att, MW, cvec);

    // node encoder (MFMA, fp32 A cast in staging): h = x @ enc_W + enc_b
    k_gemm_mfma<128, true, true, true, true>
        <<<dim3((N + 63) / 64, 2), 256, 0, stream>>>(x, encWT16, encb, h, h16, N);

    // CSR scatter via offs+rank (atomic-free) + edge logits; layer-0 rowdot
    int rb = (N + 255) / 256;
    k_fill_rd<<<eb + rb, 256, 0, stream>>>(dstIdx, srcIdx, offs, rank, eattr, MW,
                                           cvec, src_s, a_e_i, E, h, wa_sd, a_sd,
                                           N, eb);

    int ab = (N * 64 + 255) / 256;
    for (int l = 0; l < 2; ++l) {
        k_gemm_mfma<512, false, false, true, false>
            <<<dim3((N + 63) / 64, 8), 256, 0, stream>>>(
                h16, WT16 + (size_t)l * 512 * 128, nullptr, nullptr, xh16, N);
        k_agg<<<ab, 256, 0, stream>>>(
            offs, src_s, a_sd, a_e_i, xh16, outb, N, l);
        k_bnstats<<<256, 128, 0, stream>>>(outb, bnsum + l * 128, bnsumsq + l * 128, N);
        if (l == 0) {
            k_bn_apply_rd<true><<<ab, 256, 0, stream>>>(
                outb, bnsum, bnsumsq, gamma, beta, wa_sd + 1024, h, h16, a_sd, N);
        } else {
            k_bn_apply_rd<false><<<ab, 256, 0, stream>>>(
                outb, bnsum + 128, bnsumsq + 128, gamma + 128, beta + 128,
                nullptr, h, h16, nullptr, N);
        }
    }
}

// Round 17
// 235.764 us; speedup vs baseline: 1.2340x; 1.0038x over previous
//
#include <hip/hip_runtime.h>
#include <hip/hip_bf16.h>

typedef __attribute__((ext_vector_type(8))) short short8;
typedef __attribute__((ext_vector_type(4))) float f32x4;

#define DEGPAD 16   // one counter per 64B line: kills atomic line-contention

__device__ __forceinline__ unsigned short f2bf(float x) {
    unsigned int u = __float_as_uint(x);
    u += 0x7fffu + ((u >> 16) & 1u);   // round-to-nearest-even
    return (unsigned short)(u >> 16);
}

__device__ __forceinline__ unsigned int pack2(float a, float b) {
    return (unsigned int)f2bf(a) | ((unsigned int)f2bf(b) << 16);
}

__device__ __forceinline__ float2 bf2(unsigned int u) {
    float lo = __uint_as_float(u << 16);
    float hi = __uint_as_float(u & 0xffff0000u);
    return make_float2(lo, hi);
}

// zero deg counters (replaces hipMemsetAsync: runtime fill kernel measured
// ~47us fixed cost inside the graph; this is ~2us)
__global__ __launch_bounds__(256) void k_zero(int4* __restrict__ p, int n4) {
    int i = blockIdx.x * 256 + threadIdx.x;
    if (i < n4) p[i] = make_int4(0, 0, 0, 0);
}

// Merged: weight prep (blocks 0..575) + attention collapse & BN-stat zeroing
// (576..587) + degree histogram with RANK capture (588..).
__global__ __launch_bounds__(256) void k_misc1(
    const float* __restrict__ encW, const float* __restrict__ W,
    const float* __restrict__ We, const float* __restrict__ att_src,
    const float* __restrict__ att_dst, const float* __restrict__ att_edge,
    const int* __restrict__ dst,
    unsigned short* __restrict__ encWT16, unsigned short* __restrict__ WT16,
    float* __restrict__ we_att, float* __restrict__ wa_sd,
    int* __restrict__ deg, int* __restrict__ rank,
    float* __restrict__ bnz, int E_) {
    int b = blockIdx.x, t = threadIdx.x;
    if (b < 576) {
        int o = b * 256 + t;
        if (o < 16384) {
            int c = o >> 7, k = o & 127;
            encWT16[o] = f2bf(encW[k * 128 + c]);
        } else {
            int o2 = o - 16384;
            int l = o2 >> 16, r = o2 & 65535;
            int c = r >> 7, k = r & 127;
            WT16[o2] = f2bf(W[((size_t)l * 128 + k) * 512 + c]);
        }
    } else if (b < 588) {
        int o = (b - 576) * 256 + t;
        if (b < 578) bnz[o] = 0.f;   // zero bnsum/bnsumsq (512 floats)
        if (o < 1024) {
            int k = o >> 3, lh = o & 7, l = lh >> 2, hh = lh & 3;
            const float* wrow = We + ((size_t)(l * 128 + k)) * 512 + hh * 128;
            const float* av = att_edge + (l * 4 + hh) * 128;
            float s = 0.f;
            #pragma unroll 8
            for (int c = 0; c < 128; ++c) s = fmaf(wrow[c], av[c], s);
            we_att[o] = s;
        } else if (o < 3072) {
            int o2 = o - 1024;
            int l = o2 >> 10, r = o2 & 1023, k = r >> 3, m = r & 7, hh = m & 3;
            const float* wrow = W + ((size_t)(l * 128 + k)) * 512 + hh * 128;
            const float* av = (m < 4 ? att_src : att_dst) + (l * 4 + hh) * 128;
            float s = 0.f;
            #pragma unroll 8
            for (int c = 0; c < 128; ++c) s = fmaf(wrow[c], av[c], s);
            wa_sd[o2] = s;
        }
    } else {
        int e = (b - 588) * 256 + t;
        if (e < E_) rank[e] = atomicAdd(&deg[(size_t)dst[e] * DEGPAD], 1);
    }
}

// Block 0: exclusive scan of padded deg -> offs.  Block 1: MW/cvec collapse.
__global__ __launch_bounds__(1024) void k_scan_mw(
    const int* __restrict__ deg, int* __restrict__ offs, int n,
    const float* __restrict__ eencW, const float* __restrict__ eencb,
    const float* __restrict__ we_att,
    float* __restrict__ MW, float* __restrict__ cvec) {
    int t = threadIdx.x;
    if (blockIdx.x == 1) {
        if (t < 512) {
            int k = t >> 3, q = t & 7;
            float s = 0.f;
            #pragma unroll 8
            for (int c = 0; c < 128; ++c) s = fmaf(eencW[k * 128 + c], we_att[c * 8 + q], s);
            MW[t] = s;
        } else if (t < 520) {
            int q = t - 512;
            float s = 0.f;
            #pragma unroll 8
            for (int c = 0; c < 128; ++c) s = fmaf(eencb[c], we_att[c * 8 + q], s);
            cvec[q] = s;
        }
        return;
    }
    __shared__ int part[1024];
    int per = (n + 1023) / 1024;
    int beg = t * per, end = min(beg + per, n);
    int s = 0;
    for (int i = beg; i < end; ++i) s += deg[(size_t)i * DEGPAD];
    part[t] = s;
    __syncthreads();
    for (int off = 1; off < 1024; off <<= 1) {
        int v = (t >= off) ? part[t - off] : 0;
        __syncthreads();
        part[t] += v;
        __syncthreads();
    }
    int run = (t == 0) ? 0 : part[t - 1];
    for (int i = beg; i < end; ++i) { offs[i] = run; run += deg[(size_t)i * DEGPAD]; }
    if (t == 1023) offs[n] = run;
}

// MFMA GEMM: C[M][NC] = A @ B (BT16 = B^T [NC][128] bf16). A fp32 (cast in
// staging) or bf16. W32/W16 outputs, optional bias.
template <int NC, bool A32, bool W32, bool W16, bool BIAS>
__global__ __launch_bounds__(256) void k_gemm_mfma(
    const void* __restrict__ A,
    const unsigned short* __restrict__ BT16,
    const float* __restrict__ bias,
    float* __restrict__ C,
    unsigned short* __restrict__ C16, int M) {
    __shared__ unsigned short a_lds[64][136];  // +8 pad
    __shared__ unsigned short b_lds[64][136];
    int t = threadIdx.x;
    int rbase = blockIdx.x * 64;
    int cbase = blockIdx.y * 64;
    #pragma unroll
    for (int i = 0; i < 4; ++i) {
        int idx = t * 8 + i * 2048;
        int r = idx >> 7, k = idx & 127;
        if constexpr (A32) {
            const float* Af = (const float*)A;
            float4 f0 = make_float4(0.f, 0.f, 0.f, 0.f), f1 = f0;
            if (rbase + r < M) {
                f0 = *(const float4*)(Af + (size_t)(rbase + r) * 128 + k);
                f1 = *(const float4*)(Af + (size_t)(rbase + r) * 128 + k + 4);
            }
            uint4 v = make_uint4(pack2(f0.x, f0.y), pack2(f0.z, f0.w),
                                 pack2(f1.x, f1.y), pack2(f1.z, f1.w));
            *(uint4*)&a_lds[r][k] = v;
        } else {
            const unsigned short* Ah = (const unsigned short*)A;
            uint4 v = make_uint4(0u, 0u, 0u, 0u);
            if (rbase + r < M) v = *(const uint4*)(Ah + (size_t)(rbase + r) * 128 + k);
            *(uint4*)&a_lds[r][k] = v;
        }
    }
    #pragma unroll
    for (int i = 0; i < 4; ++i) {
        int idx = t * 8 + i * 2048;
        int r = idx >> 7, k = idx & 127;
        uint4 v = *(const uint4*)(BT16 + (size_t)(cbase + r) * 128 + k);
        *(uint4*)&b_lds[r][k] = v;
    }
    __syncthreads();
    int lane = t & 63, w = t >> 6;
    int lr = lane & 15, lk = (lane >> 4) * 8;
    f32x4 acc[4] = {f32x4{0.f, 0.f, 0.f, 0.f}, f32x4{0.f, 0.f, 0.f, 0.f},
                    f32x4{0.f, 0.f, 0.f, 0.f}, f32x4{0.f, 0.f, 0.f, 0.f}};
    #pragma unroll
    for (int kt = 0; kt < 4; ++kt) {
        short8 a = *(const short8*)&a_lds[w * 16 + lr][kt * 32 + lk];
        #pragma unroll
        for (int ct = 0; ct < 4; ++ct) {
            short8 b = *(const short8*)&b_lds[ct * 16 + lr][kt * 32 + lk];
            acc[ct] = __builtin_amdgcn_mfma_f32_16x16x32_bf16(a, b, acc[ct], 0, 0, 0);
        }
    }
    int rw = rbase + w * 16 + (lane >> 4) * 4;
    #pragma unroll
    for (int ct = 0; ct < 4; ++ct) {
        int col = cbase + ct * 16 + lr;
        float bv = 0.f;
        if constexpr (BIAS) bv = bias[col];
        #pragma unroll
        for (int j = 0; j < 4; ++j) {
            int r = rw + j;
            if (r < M) {
                float v = acc[ct][j] + bv;
                if constexpr (W32) C[(size_t)r * NC + col] = v;
                if constexpr (W16) C16[(size_t)r * NC + col] = f2bf(v);
            }
        }
    }
}

// Merged: CSR scatter + edge-attention matvec (blocks < fillBlocks; row per
// thread, mw in LDS read at UNIFORM addresses -> broadcast, conflict-free)
// and layer-0 rowdot a_sd (remaining blocks). Slot = offs[dst] + rank.
__global__ __launch_bounds__(256) void k_fill_rd(
    const int* __restrict__ dst, const int* __restrict__ src,
    const int* __restrict__ offs, const int* __restrict__ rank,
    const float* __restrict__ eattr, const float* __restrict__ MW,
    const float* __restrict__ cvec,
    int* __restrict__ src_s, float* __restrict__ a_e_i, int E_,
    const float* __restrict__ X, const float* __restrict__ V,
    float* __restrict__ O, int M, int fillBlocks) {
    int t = threadIdx.x;
    if ((int)blockIdx.x < fillBlocks) {
        __shared__ float mw[64][8];
        __shared__ float cv[8];
        for (int i = t; i < 512; i += 256) mw[i >> 3][i & 7] = MW[i];
        if (t < 8) cv[t] = cvec[t];
        __syncthreads();
        int e = blockIdx.x * 256 + t;
        if (e >= E_) return;
        int d = dst[e];
        int pos = offs[d] + rank[e];
        float acc[8];
        #pragma unroll
        for (int q = 0; q < 8; ++q) acc[q] = cv[q];
        const float4* r = (const float4*)(eattr + (size_t)e * 64);
        #pragma unroll 4
        for (int k4 = 0; k4 < 16; ++k4) {
            float4 v = r[k4];
            float xc[4] = {v.x, v.y, v.z, v.w};
            #pragma unroll
            for (int m = 0; m < 4; ++m)
                #pragma unroll
                for (int q = 0; q < 8; ++q)
                    acc[q] = fmaf(xc[m], mw[k4 * 4 + m][q], acc[q]);
        }
        src_s[pos] = src[e];
        *(float4*)(a_e_i + (size_t)pos * 8) = make_float4(acc[0], acc[1], acc[2], acc[3]);
        *(float4*)(a_e_i + (size_t)pos * 8 + 4) = make_float4(acc[4], acc[5], acc[6], acc[7]);
    } else {
        __shared__ float v_lds[128][8];
        for (int idx = t; idx < 1024; idx += 256) v_lds[idx >> 3][idx & 7] = V[idx];
        __syncthreads();
        int row = (blockIdx.x - fillBlocks) * 256 + t;
        if (row >= M) return;
        float acc[8] = {};
        const float4* x4 = (const float4*)(X + (size_t)row * 128);
        for (int k4 = 0; k4 < 32; ++k4) {
            float4 xv = x4[k4];
            float xc[4] = {xv.x, xv.y, xv.z, xv.w};
            #pragma unroll
            for (int m = 0; m < 4; ++m)
                #pragma unroll
                for (int o = 0; o < 8; ++o) acc[o] = fmaf(xc[m], v_lds[k4 * 4 + m][o], acc[o]);
        }
        *(float4*)(O + (size_t)row * 8) = make_float4(acc[0], acc[1], acc[2], acc[3]);
        *(float4*)(O + (size_t)row * 8 + 4) = make_float4(acc[4], acc[5], acc[6], acc[7]);
    }
}

// Fused softmax+gather, one edge sweep, UNROLL-2 with independent chains
// (dual accumulators + pair-ahead src prefetch). Wave per node; lane l:
// head l>>4, channels (l&15)*8..+7, one uint4/edge. Shift-free softmax;
// self-loop edge logit = running mean; bias dropped (BN absorbs). No
// trailing block barrier — waves retire independently.
__global__ __launch_bounds__(256) void k_agg(
    const int* __restrict__ offs, const int* __restrict__ src_s,
    const float* __restrict__ a_sd, const float* __restrict__ a_e_i,
    const unsigned short* __restrict__ xh16,
    float* __restrict__ outb, int N_, int lsel) {
    int wid = (blockIdx.x * 256 + threadIdx.x) >> 6;
    int lane = threadIdx.x & 63;
    if (wid >= N_) return;
    int n = wid;
    int s0 = offs[n], s1 = offs[n + 1];
    int hsel = lane >> 4;
    int qoff = lsel * 4 + hsel;
    float ad = a_sd[(size_t)n * 8 + 4 + hsel];
    float acc[8] = {}, acc2[8] = {};
    float ssum = 0.f, ssum2 = 0.f, macc = 0.f;
    int idx = s0;
    int sa_n = 0, sb_n = 0;
    if (idx + 1 < s1) { sa_n = src_s[idx]; sb_n = src_s[idx + 1]; }
    for (; idx + 1 < s1; idx += 2) {
        int sa = sa_n, sb = sb_n;
        if (idx + 3 < s1) { sa_n = src_s[idx + 2]; sb_n = src_s[idx + 3]; }
        float aea = a_e_i[(size_t)idx * 8 + qoff];
        float aeb = a_e_i[(size_t)(idx + 1) * 8 + qoff];
        float asa = a_sd[(size_t)sa * 8 + hsel];
        float asb = a_sd[(size_t)sb * 8 + hsel];
        uint4 va = *(const uint4*)(xh16 + (size_t)sa * 512 + lane * 8);
        uint4 vb = *(const uint4*)(xh16 + (size_t)sb * 512 + lane * 8);
        macc += aea + aeb;
        float ra = asa + aea + ad;
        ra = ra >= 0.f ? ra : 0.2f * ra;
        float rb = asb + aeb + ad;
        rb = rb >= 0.f ? rb : 0.2f * rb;
        float exa = __expf(ra), exb = __expf(rb);
        ssum += exa;
        ssum2 += exb;
        float2 a0 = bf2(va.x), a1 = bf2(va.y), a2 = bf2(va.z), a3 = bf2(va.w);
        float2 b0 = bf2(vb.x), b1 = bf2(vb.y), b2 = bf2(vb.z), b3 = bf2(vb.w);
        acc[0] = fmaf(exa, a0.x, acc[0]);  acc[1] = fmaf(exa, a0.y, acc[1]);
        acc[2] = fmaf(exa, a1.x, acc[2]);  acc[3] = fmaf(exa, a1.y, acc[3]);
        acc[4] = fmaf(exa, a2.x, acc[4]);  acc[5] = fmaf(exa, a2.y, acc[5]);
        acc[6] = fmaf(exa, a3.x, acc[6]);  acc[7] = fmaf(exa, a3.y, acc[7]);
        acc2[0] = fmaf(exb, b0.x, acc2[0]); acc2[1] = fmaf(exb, b0.y, acc2[1]);
        acc2[2] = fmaf(exb, b1.x, acc2[2]); acc2[3] = fmaf(exb, b1.y, acc2[3]);
        acc2[4] = fmaf(exb, b2.x, acc2[4]); acc2[5] = fmaf(exb, b2.y, acc2[5]);
        acc2[6] = fmaf(exb, b3.x, acc2[6]); acc2[7] = fmaf(exb, b3.y, acc2[7]);
    }
    if (idx < s1) {   // tail edge
        int sn = src_s[idx];
        float ae = a_e_i[(size_t)idx * 8 + qoff];
        float as = a_sd[(size_t)sn * 8 + hsel];
        uint4 v = *(const uint4*)(xh16 + (size_t)sn * 512 + lane * 8);
        macc += ae;
        float raw = as + ae + ad;
        raw = raw >= 0.f ? raw : 0.2f * raw;
        float ex = __expf(raw);
        ssum += ex;
        float2 p0 = bf2(v.x), p1 = bf2(v.y), p2 = bf2(v.z), p3 = bf2(v.w);
        acc[0] = fmaf(ex, p0.x, acc[0]); acc[1] = fmaf(ex, p0.y, acc[1]);
        acc[2] = fmaf(ex, p1.x, acc[2]); acc[3] = fmaf(ex, p1.y, acc[3]);
        acc[4] = fmaf(ex, p2.x, acc[4]); acc[5] = fmaf(ex, p2.y, acc[5]);
        acc[6] = fmaf(ex, p3.x, acc[6]); acc[7] = fmaf(ex, p3.y, acc[7]);
    }
    ssum += ssum2;
    #pragma unroll
    for (int q = 0; q < 8; ++q) acc[q] += acc2[q];
    {   // self loop: edge-feature logit = mean of in-edge logits (fill='mean')
        float dg = (float)max(s1 - s0, 1);
        float ae = macc / dg;
        float as = a_sd[(size_t)n * 8 + hsel];
        float raw = as + ae + ad;
        raw = raw >= 0.f ? raw : 0.2f * raw;
        float ex = __expf(raw);
        ssum += ex;
        uint4 v = *(const uint4*)(xh16 + (size_t)n * 512 + lane * 8);
        float2 p0 = bf2(v.x), p1 = bf2(v.y), p2 = bf2(v.z), p3 = bf2(v.w);
        acc[0] = fmaf(ex, p0.x, acc[0]); acc[1] = fmaf(ex, p0.y, acc[1]);
        acc[2] = fmaf(ex, p1.x, acc[2]); acc[3] = fmaf(ex, p1.y, acc[3]);
        acc[4] = fmaf(ex, p2.x, acc[4]); acc[5] = fmaf(ex, p2.y, acc[5]);
        acc[6] = fmaf(ex, p3.x, acc[6]); acc[7] = fmaf(ex, p3.y, acc[7]);
    }
    float inv = 0.25f / (ssum + 1e-16f);   // head-mean folded in
    #pragma unroll
    for (int q = 0; q < 8; ++q) acc[q] *= inv;
    // sum across the 4 head groups (lanes l, l^16, l^32, l^48)
    #pragma unroll
    for (int off = 16; off <= 32; off <<= 1)
        #pragma unroll
        for (int q = 0; q < 8; ++q) acc[q] += __shfl_xor(acc[q], off);
    if (lane < 16) {
        float* orow = outb + (size_t)n * 128 + lane * 8;
        *(float4*)orow = make_float4(acc[0], acc[1], acc[2], acc[3]);
        *(float4*)(orow + 4) = make_float4(acc[4], acc[5], acc[6], acc[7]);
    }
}

__global__ __launch_bounds__(128) void k_bnstats(const float* __restrict__ outb,
                                                 float* __restrict__ bnsum,
                                                 float* __restrict__ bnsumsq, int N_) {
    int c = threadIdx.x;
    float s = 0.f, s2 = 0.f;
    for (int r = blockIdx.x; r < N_; r += gridDim.x) {
        float v = outb[(size_t)r * 128 + c];
        s += v;
        s2 = fmaf(v, v, s2);
    }
    atomicAdd(&bnsum[c], s);
    atomicAdd(&bnsumsq[c], s2);
}

// BN apply + residual + relu; optionally fused next-layer a_sd rowdot.
template <bool DOROW>
__global__ __launch_bounds__(256) void k_bn_apply_rd(
    const float* __restrict__ outb, const float* __restrict__ bnsum,
    const float* __restrict__ bnsumsq, const float* __restrict__ gamma,
    const float* __restrict__ beta, const float* __restrict__ wa,
    float* __restrict__ h, unsigned short* __restrict__ h16,
    float* __restrict__ a_sd, int N_) {
    __shared__ float wlds[128][8];
    int t = threadIdx.x;
    if constexpr (DOROW) {
        for (int i = t; i < 1024; i += 256) wlds[i >> 3][i & 7] = wa[i];
        __syncthreads();
    }
    int wid = (blockIdx.x * 256 + t) >> 6;
    int lane = t & 63;
    if (wid >= N_) return;
    int n = wid;
    float invN = 1.0f / (float)N_;
    int c0 = lane, c1 = lane + 64;
    float mu0 = bnsum[c0] * invN, mu1 = bnsum[c1] * invN;
    float g0 = rsqrtf(bnsumsq[c0] * invN - mu0 * mu0 + 1e-5f) * gamma[c0];
    float g1 = rsqrtf(bnsumsq[c1] * invN - mu1 * mu1 + 1e-5f) * gamma[c1];
    float o0 = outb[(size_t)n * 128 + c0], o1 = outb[(size_t)n * 128 + c1];
    float v0 = (o0 - mu0) * g0 + beta[c0];
    float v1 = (o1 - mu1) * g1 + beta[c1];
    float nh0 = h[(size_t)n * 128 + c0] + fmaxf(v0, 0.f);
    float nh1 = h[(size_t)n * 128 + c1] + fmaxf(v1, 0.f);
    h[(size_t)n * 128 + c0] = nh0;
    h[(size_t)n * 128 + c1] = nh1;
    h16[(size_t)n * 128 + c0] = f2bf(nh0);
    h16[(size_t)n * 128 + c1] = f2bf(nh1);
    if constexpr (DOROW) {
        float p[8];
        #pragma unroll
        for (int m = 0; m < 8; ++m)
            p[m] = fmaf(nh0, wlds[c0][m], nh1 * wlds[c1][m]);
        #pragma unroll
        for (int off = 1; off < 64; off <<= 1)
            #pragma unroll
            for (int m = 0; m < 8; ++m) p[m] += __shfl_xor(p[m], off);
        if (lane == 0) {
            *(float4*)(a_sd + (size_t)n * 8) = make_float4(p[0], p[1], p[2], p[3]);
            *(float4*)(a_sd + (size_t)n * 8 + 4) = make_float4(p[4], p[5], p[6], p[7]);
        }
    }
}

extern "C" void kernel_launch(void* const* d_in, const int* in_sizes, int n_in,
                              void* d_out, int out_size, void* d_ws, size_t ws_size,
                              hipStream_t stream) {
    const float* x = (const float*)d_in[0];
    const int* ei = (const int*)d_in[1];
    const float* eattr = (const float*)d_in[2];
    const float* encW = (const float*)d_in[4];
    const float* encb = (const float*)d_in[5];
    const float* eencW = (const float*)d_in[6];
    const float* eencb = (const float*)d_in[7];
    const float* W = (const float*)d_in[8];
    const float* We = (const float*)d_in[9];
    const float* att_src = (const float*)d_in[10];
    const float* att_dst = (const float*)d_in[11];
    const float* att_edge = (const float*)d_in[12];
    const float* gamma = (const float*)d_in[14];
    const float* beta = (const float*)d_in[15];

    const int N = in_sizes[0] / 128;
    const int E = in_sizes[1] / 2;
    const int* srcIdx = ei;
    const int* dstIdx = ei + E;
    float* h = (float*)d_out;

    char* wbase = (char*)d_ws;
    size_t off = 0;
    auto alloc = [&](size_t bytes) -> void* {
        void* p = wbase + off;
        off = (off + bytes + 255) & ~(size_t)255;
        return p;
    };
    unsigned short* encWT16 = (unsigned short*)alloc((size_t)128 * 128 * 2);
    unsigned short* WT16 = (unsigned short*)alloc((size_t)2 * 512 * 128 * 2);
    float* we_att = (float*)alloc((size_t)128 * 8 * 4);
    float* wa_sd = (float*)alloc((size_t)2 * 128 * 8 * 4);
    float* MW = (float*)alloc((size_t)64 * 8 * 4);
    float* cvec = (float*)alloc((size_t)8 * 4);
    int* deg = (int*)alloc((size_t)N * DEGPAD * 4);  // padded counters
    int* rank = (int*)alloc((size_t)E * 4);
    int* offs = (int*)alloc((size_t)(N + 1) * 4);
    int* src_s = (int*)alloc((size_t)E * 4);
    float* a_e_i = (float*)alloc((size_t)E * 8 * 4);   // interleaved [pos][8]
    float* a_sd = (float*)alloc((size_t)N * 8 * 4);
    unsigned short* h16 = (unsigned short*)alloc((size_t)N * 128 * 2);
    unsigned short* xh16 = (unsigned short*)alloc((size_t)N * 512 * 2);  // [N][512]
    float* outb = (float*)alloc((size_t)N * 128 * 4);
    float* bnsum = (float*)alloc((size_t)4 * 128 * 4);
    float* bnsumsq = bnsum + 2 * 128;
    (void)ws_size; (void)n_in; (void)out_size;

    // zero deg with our own kernel (runtime fill kernel costs ~47us in-graph)
    int zn4 = (N * DEGPAD) / 4;
    k_zero<<<(zn4 + 255) / 256, 256, 0, stream>>>((int4*)deg, zn4);

    int eb = (E + 255) / 256;
    // prep + attention collapse + bn zero + degree histogram w/ rank capture
    k_misc1<<<588 + eb, 256, 0, stream>>>(encW, W, We, att_src, att_dst, att_edge,
                                          dstIdx, encWT16, WT16, we_att, wa_sd,
                                          deg, rank, bnsum, E);
    // scan (block 0) + MW collapse (block 1)
    k_scan_mw<<<2, 1024, 0, stream>>>(deg, offs, N, eencW, eencb, we_att, MW, cvec);

    // node encoder (MFMA, fp32 A cast in staging): h = x @ enc_W + enc_b
    k_gemm_mfma<128, true, true, true, true>
        <<<dim3((N + 63) / 64, 2), 256, 0, stream>>>(x, encWT16, encb, h, h16, N);

    // CSR scatter via offs+rank (atomic-free) + edge logits; layer-0 rowdot
    int rb = (N + 255) / 256;
    k_fill_rd<<<eb + rb, 256, 0, stream>>>(dstIdx, srcIdx, offs, rank, eattr, MW,
                                           cvec, src_s, a_e_i, E, h, wa_sd, a_sd,
                                           N, eb);

    int ab = (N * 64 + 255) / 256;
    for (int l = 0; l < 2; ++l) {
        k_gemm_mfma<512, false, false, true, false>
            <<<dim3((N + 63) / 64, 8), 256, 0, stream>>>(
                h16, WT16 + (size_t)l * 512 * 128, nullptr, nullptr, xh16, N);
        k_agg<<<ab, 256, 0, stream>>>(
            offs, src_s, a_sd, a_e_i, xh16, outb, N, l);
        k_bnstats<<<256, 128, 0, stream>>>(outb, bnsum + l * 128, bnsumsq + l * 128, N);
        if (l == 0) {
            k_bn_apply_rd<true><<<ab, 256, 0, stream>>>(
                outb, bnsum, bnsumsq, gamma, beta, wa_sd + 1024, h, h16, a_sd, N);
        } else {
            k_bn_apply_rd<false><<<ab, 256, 0, stream>>>(
                outb, bnsum + 128, bnsumsq + 128, gamma + 128, beta + 128,
                nullptr, h, h16, nullptr, N);
        }
    }
}